// Round 10
// baseline (106.396 us; speedup 1.0000x reference)
//
#include <hip/hip_runtime.h>
#include <stdint.h>

#define BATCH 1024
#define DIM 768
#define NBLK 64

typedef unsigned long long u64;
typedef __attribute__((ext_vector_type(8))) short short8;  // 8 bf16 = 4 VGPRs
typedef __attribute__((ext_vector_type(4))) float f32x4;

// Workspace layout (bytes):
//   [0]      float acc                 (zeroed by prep block 0)
//   [8]      int   donecnt             (zeroed by prep block 0)
//   [49152]  ushort txtB[1024*768]     (1.5 MB) bf16, MFMA B-frag order
// B-frag order: off(col,k) = ((k>>5)*64 + (col>>4))*512 + ((k>>3)&3)*128
//                            + (col&15)*8 + (k&7)
#define WS_ACC      0
#define WS_DONE     8
#define WS_TXTB 49152

__device__ __forceinline__ unsigned short to_bf16(float x) {
    unsigned int u = __float_as_uint(x);
    return (unsigned short)((u + 0x7FFFu + ((u >> 16) & 1u)) >> 16);  // RNE
}

// ---------------------------------------------------------------------------
// K1: txt fp32 -> bf16 B-frag order + zero acc/donecnt. 256 blocks x 256
// threads. (R7-proven body; init targets changed only.)
// ---------------------------------------------------------------------------
__global__ __launch_bounds__(256) void prep_kernel(
        const float* __restrict__ txt, float* __restrict__ acc,
        int* __restrict__ donecnt, unsigned short* __restrict__ txtB) {
    if (blockIdx.x == 0 && threadIdx.x == 0) { *acc = 0.0f; *donecnt = 0; }
    const int wave = threadIdx.x >> 6;
    const int lane = threadIdx.x & 63;

    for (int i = wave; i < 6; i += 4) {
        const int G  = blockIdx.x * 6 + i;
        const int tt = G / 24;        // col-tile 0..63
        const int g  = G - tt * 24;   // k-group 0..23
        const int col = tt * 16 + (lane & 15);
        const int k0  = g * 32 + (lane >> 4) * 8;
        const float4 va = *(const float4*)(txt + (size_t)col * DIM + k0);
        const float4 vb = *(const float4*)(txt + (size_t)col * DIM + k0 + 4);
        short8 hv = {(short)to_bf16(va.x), (short)to_bf16(va.y),
                     (short)to_bf16(va.z), (short)to_bf16(va.w),
                     (short)to_bf16(vb.x), (short)to_bf16(vb.y),
                     (short)to_bf16(vb.z), (short)to_bf16(vb.w)};
        *(short8*)(txtB + (size_t)(g * 64 + tt) * 512 + lane * 8) = hv;
    }
}

// ---------------------------------------------------------------------------
// K2: full-row GEMM + complete in-block softmax/label/loss. 64 blocks x
// 1024 threads (1 block/CU, 90.8 KB LDS). Block = 16 rows x 1024 cols;
// wave w owns col-tiles {4w..4w+3} in the k-loop and row r0+w in the
// epilogue. NO cross-block publishes, NO tail barrier, NO acquire fence —
// epilogue is one atomicAdd(acc)+done-counter (64-deep; R8-proven
// arrival-order summation, minus R8's 1024-deep contention mistake).
//
// Bitwise-preserved math vs R7 (absmax 0.0 lineage):
//  - stage A verbatim; C layout col=l15,row=quad*4+r verbatim
//  - per-(row, 256-col-chunk) partials: same float4 grouping, same
//    fmaxf/shfl_xor trees, same 4-way gmax/ss/lse combine
//  - label scan + exact float== verify + fp32 label dot verbatim
// ---------------------------------------------------------------------------
#define LSTRIDE 1036   // floats; rows 16B-aligned, quad-rows bank-offset 16

__global__ __launch_bounds__(1024) void gemm_fused(
        const float* __restrict__ img, const float* __restrict__ txt,
        const float* __restrict__ scale_p, const unsigned short* __restrict__ txtB,
        float* __restrict__ acc_g, int* __restrict__ donecnt,
        float* __restrict__ out) {
    __shared__ unsigned short Ahi[16 * DIM];       // 24 KB, A-frag order
    __shared__ float logitsS[16][LSTRIDE];         // 66.3 KB
    __shared__ float part[16];

    const int tid  = threadIdx.x;
    const int wave = tid >> 6;
    const int lane = tid & 63;
    const int quad = lane >> 4;
    const int l15  = lane & 15;
    const int r0   = blockIdx.x * 16;

    // stage A: wave w converts img row r0+w into frag order (R7 verbatim)
    {
        const float* ir = img + (size_t)(r0 + wave) * DIM;
#pragma unroll
        for (int j = 0; j < 12; ++j) {
            const int k = lane + j * 64;
            Ahi[((k >> 3) * 16 + wave) * 8 + (k & 7)] = to_bf16(ir[k]);
        }
    }
    __syncthreads();

    // k-loop: wave w owns col-tiles 4w+q; A-frag shared across the 4 MFMAs
    const int foff = quad * 128 + l15 * 8;
    f32x4 acc[4] = {{0.f,0.f,0.f,0.f},{0.f,0.f,0.f,0.f},
                    {0.f,0.f,0.f,0.f},{0.f,0.f,0.f,0.f}};
#pragma unroll
    for (int kk = 0; kk < 24; ++kk) {
        const short8 a = *(const short8*)&Ahi[kk * 512 + foff];
#pragma unroll
        for (int q = 0; q < 4; ++q) {
            const int tt = wave * 4 + q;
            const short8 b = *(const short8*)(txtB + (size_t)(kk * 64 + tt) * 512 + foff);
            acc[q] = __builtin_amdgcn_mfma_f32_16x16x32_bf16(a, b, acc[q], 0, 0, 0);
        }
    }

    // C layout: col = l15, row = quad*4 + r  [verified, absmax 0.0]
    const float scale = scale_p[0];
#pragma unroll
    for (int q = 0; q < 4; ++q)
#pragma unroll
        for (int r = 0; r < 4; ++r)
            logitsS[quad * 4 + r][wave * 64 + q * 16 + l15] = scale * acc[q][r];
    __syncthreads();

    // wave w = row r0+w: 4 chunk partials (same grouping/trees as R7),
    // then the SAME 4-way combine formula as the R7 tail.
    float pm[4], ps[4];
#pragma unroll
    for (int c = 0; c < 4; ++c) {
        const float4 f = *(const float4*)&logitsS[wave][c * 256 + lane * 4];
        float mx = fmaxf(fmaxf(f.x, f.y), fmaxf(f.z, f.w));
#pragma unroll
        for (int s = 32; s; s >>= 1) mx = fmaxf(mx, __shfl_xor(mx, s, 64));
        float sum = __expf(f.x - mx) + __expf(f.y - mx) +
                    __expf(f.z - mx) + __expf(f.w - mx);
#pragma unroll
        for (int s = 32; s; s >>= 1) sum += __shfl_xor(sum, s, 64);
        pm[c] = mx; ps[c] = sum;
    }
    const float gmax = fmaxf(fmaxf(pm[0], pm[1]), fmaxf(pm[2], pm[3]));
    const float ss = ps[0] * __expf(pm[0] - gmax) + ps[1] * __expf(pm[1] - gmax)
                   + ps[2] * __expf(pm[2] - gmax) + ps[3] * __expf(pm[3] - gmax);
    const float lse = gmax + __logf(ss);

    // label: wave w owns row j = r0+w (R7 scan verbatim)
    const int j = r0 + wave;
    float loss;
    {
        const float2 sj = *(const float2*)(img + (size_t)j * DIM);
        int lo = -1;
        int label = j;
        for (;;) {
            int cand = BATCH;
#pragma unroll
            for (int it = 0; it < 16; ++it) {
                const int i = lane + it * 64;          // always < 1024
                const float2 si = *(const float2*)(img + (size_t)i * DIM);
                if (i < j && i > lo && si.x == sj.x && si.y == sj.y)
                    cand = min(cand, i);
            }
#pragma unroll
            for (int s = 32; s; s >>= 1) cand = min(cand, __shfl_xor(cand, s, 64));
            if (cand >= j) break;                      // no candidate -> label = j
            const float4* rpm = (const float4*)(img + (size_t)cand * DIM);
            const float4* rpj = (const float4*)(img + (size_t)j * DIM);
            bool eq = true;
#pragma unroll
            for (int cc = 0; cc < 3; ++cc) {
                float4 vm = rpm[cc * 64 + lane];
                float4 vj = rpj[cc * 64 + lane];
                eq = eq && (vm.x == vj.x) && (vm.y == vj.y) &&
                     (vm.z == vj.z) && (vm.w == vj.w);
            }
            if (__all(eq)) { label = cand; break; }
            lo = cand;                                 // false positive: rescan above
        }

        // exact fp32 label logit: scale * dot(img[j], txt[label]) (verbatim)
        const float4* aj = (const float4*)(img + (size_t)j * DIM);
        const float4* bl = (const float4*)(txt + (size_t)label * DIM);
        float s = 0.0f;
#pragma unroll
        for (int cc = 0; cc < 3; ++cc) {
            const float4 va = aj[cc * 64 + lane];
            const float4 vb = bl[cc * 64 + lane];
            s += va.x * vb.x + va.y * vb.y + va.z * vb.z + va.w * vb.w;
        }
#pragma unroll
        for (int m = 32; m; m >>= 1) s += __shfl_xor(s, m, 64);
        loss = lse - scale * s;                        // same lse - lval formula
    }

    if (lane == 0) part[wave] = loss;
    __syncthreads();
    if (tid == 0) {
        float bl = 0.0f;
#pragma unroll
        for (int w = 0; w < 16; ++w) bl += part[w];
        const float ao = atomicAdd(acc_g, bl);
        asm volatile("" :: "v"(ao));        // drain: acc add complete at coherent pt
        const int old = atomicAdd(donecnt, 1);
        if (old == NBLK - 1) {
            const float tot = atomicAdd(acc_g, 0.0f);  // RMW read: all adds landed
            out[0] = tot * (1.0f / BATCH);
        }
    }
}

extern "C" void kernel_launch(void* const* d_in, const int* in_sizes, int n_in,
                              void* d_out, int out_size, void* d_ws, size_t ws_size,
                              hipStream_t stream) {
    const float* img   = (const float*)d_in[0];
    const float* txt   = (const float*)d_in[1];
    const float* scale = (const float*)d_in[2];
    float* out = (float*)d_out;
    char* ws = (char*)d_ws;

    float* acc     = (float*)(ws + WS_ACC);
    int*   donecnt = (int*)(ws + WS_DONE);
    unsigned short* txtB = (unsigned short*)(ws + WS_TXTB);

    prep_kernel<<<256, 256, 0, stream>>>(txt, acc, donecnt, txtB);
    gemm_fused<<<NBLK, 1024, 0, stream>>>(img, txt, scale, txtB,
                                          acc, donecnt, out);
}

// Round 11
// 78.561 us; speedup vs baseline: 1.3543x; 1.3543x over previous
//
#include <hip/hip_runtime.h>
#include <stdint.h>

#define BATCH 1024
#define DIM 768

typedef unsigned long long u64;
typedef __attribute__((ext_vector_type(8))) short short8;  // 8 bf16 = 4 VGPRs
typedef __attribute__((ext_vector_type(4))) float f32x4;

// Workspace layout (bytes):
//   [0]      int   tailcnt             (zeroed by prep block 0)
//   [4096]   float pmax[1024*4]        (16 KB) per-row per-chunk max
//   [20480]  float psum[1024*4]        (16 KB) per-row per-chunk sumexp
//   [36864]  float lval[1024]          (4 KB)  exact fp32 label logit per row
//   [49152]  ushort txtB[1024*768]     (1.5 MB) bf16, MFMA B-frag order
// B-frag order: off(col,k) = ((k>>5)*64 + (col>>4))*512 + ((k>>3)&3)*128
//                            + (col&15)*8 + (k&7)
// -> a wave's 16x16x32 B-fragment is one contiguous 1 KB run (16 B/lane).
#define WS_TAIL     0
#define WS_PMAX  4096
#define WS_PSUM 20480
#define WS_LVAL 36864
#define WS_TXTB 49152

__device__ __forceinline__ unsigned short to_bf16(float x) {
    unsigned int u = __float_as_uint(x);
    return (unsigned short)((u + 0x7FFFu + ((u >> 16) & 1u)) >> 16);  // RNE
}

// ---------------------------------------------------------------------------
// K1: txt fp32 -> bf16 B-frag order + zero tailcnt. 256 blocks x 256 threads.
// (R7-proven, unchanged.)
// ---------------------------------------------------------------------------
__global__ __launch_bounds__(256) void prep_kernel(
        const float* __restrict__ txt, int* __restrict__ tailcnt,
        unsigned short* __restrict__ txtB) {
    if (blockIdx.x == 0 && threadIdx.x == 0) { *tailcnt = 0; }
    const int wave = threadIdx.x >> 6;
    const int lane = threadIdx.x & 63;

    for (int i = wave; i < 6; i += 4) {
        const int G  = blockIdx.x * 6 + i;
        const int tt = G / 24;        // col-tile 0..63
        const int g  = G - tt * 24;   // k-group 0..23
        const int col = tt * 16 + (lane & 15);
        const int k0  = g * 32 + (lane >> 4) * 8;
        const float4 va = *(const float4*)(txt + (size_t)col * DIM + k0);
        const float4 vb = *(const float4*)(txt + (size_t)col * DIM + k0 + 4);
        short8 hv = {(short)to_bf16(va.x), (short)to_bf16(va.y),
                     (short)to_bf16(va.z), (short)to_bf16(va.w),
                     (short)to_bf16(vb.x), (short)to_bf16(vb.y),
                     (short)to_bf16(vb.z), (short)to_bf16(vb.w)};
        *(short8*)(txtB + (size_t)(g * 64 + tt) * 512 + lane * 8) = hv;
    }
}

// ---------------------------------------------------------------------------
// K2: MFMA GEMM + softmax partials + labels + label logit + last-block
// combine. 256 blocks x 1024 thr. R7-proven body with ONE change:
// depth-6 register-prefetch ring for the B-frag loads. R10's measured
// counters (VGPR=52, MfmaUtil 1.2%, 47 us) proved the compiler keeps only
// ~2 B loads in flight -> each MFMA pays full L2/cross-XCD latency.
// pre[kk%6] with fully-unrolled kk is static-indexed (registers, +24 VGPR,
// block still fits 16 waves at <=128 VGPR). Same loads, same accumulation
// order -> bit-identical result.
// ---------------------------------------------------------------------------
__global__ __launch_bounds__(1024) void gemm_fused(
        const float* __restrict__ img, const float* __restrict__ txt,
        const float* __restrict__ scale_p, const unsigned short* __restrict__ txtB,
        float* __restrict__ pmax, float* __restrict__ psum,
        float* __restrict__ lval, int* __restrict__ tailcnt,
        float* __restrict__ out) {
    __shared__ unsigned short Ahi[16 * DIM];   // 24 KB, A-frag order
    __shared__ float logitsS[16 * 260];        // 16.6 KB (+4 pad vs bank stride)
    __shared__ int isLast;
    __shared__ float part[16];

    const int tid  = threadIdx.x;
    const int wave = tid >> 6;
    const int lane = tid & 63;
    const int quad = lane >> 4;
    const int l15  = lane & 15;
    const int r0    = (blockIdx.x >> 2) * 16;
    const int chunk = blockIdx.x & 3;

    // stage A: wave w converts img row r0+w into frag order (R7 verbatim)
    {
        const float* ir = img + (size_t)(r0 + wave) * DIM;
#pragma unroll
        for (int j = 0; j < 12; ++j) {
            const int k = lane + j * 64;
            Ahi[((k >> 3) * 16 + wave) * 8 + (k & 7)] = to_bf16(ir[k]);
        }
    }
    __syncthreads();

    // k-loop: wave's global col-tile t; B-frag kk lives at
    // bbase + kk*32768 shorts (contiguous 1 KB per wave, 16 B/lane).
    // Depth-6 prefetch ring keeps 6 loads in flight.
    const int t = chunk * 16 + wave;
    const int foff = quad * 128 + l15 * 8;
    const unsigned short* bbase = txtB + (size_t)t * 512 + foff;
    short8 pre[6];
#pragma unroll
    for (int i = 0; i < 6; ++i)
        pre[i] = *(const short8*)(bbase + (size_t)i * 32768);

    f32x4 acc = {0.f, 0.f, 0.f, 0.f};
#pragma unroll
    for (int kk = 0; kk < 24; ++kk) {
        const short8 a = *(const short8*)&Ahi[kk * 512 + foff];
        acc = __builtin_amdgcn_mfma_f32_16x16x32_bf16(a, pre[kk % 6], acc, 0, 0, 0);
        if (kk + 6 < 24)
            pre[kk % 6] = *(const short8*)(bbase + (size_t)(kk + 6) * 32768);
    }

    // C layout: col = l15, row = quad*4 + r  [verified, absmax 0.0]
    const float scale = scale_p[0];
#pragma unroll
    for (int r = 0; r < 4; ++r)
        logitsS[(quad * 4 + r) * 260 + wave * 16 + l15] = scale * acc[r];
    __syncthreads();

    // per-row partials: wave w = row r0+w; 4 floats/lane over 256 cols
    {
        const float4 f = *(const float4*)&logitsS[wave * 260 + lane * 4];
        float mx = fmaxf(fmaxf(f.x, f.y), fmaxf(f.z, f.w));
#pragma unroll
        for (int s = 32; s; s >>= 1) mx = fmaxf(mx, __shfl_xor(mx, s, 64));
        float sum = __expf(f.x - mx) + __expf(f.y - mx) +
                    __expf(f.z - mx) + __expf(f.w - mx);
#pragma unroll
        for (int s = 32; s; s >>= 1) sum += __shfl_xor(sum, s, 64);
        if (lane == 0) {
            atomicExch(&pmax[(r0 + wave) * 4 + chunk], mx);
            atomicExch(&psum[(r0 + wave) * 4 + chunk], sum);
        }
    }

    // labels: waves 0..3 handle row j = r0 + chunk*4 + wave (R7 verbatim)
    if (wave < 4) {
        const int j = r0 + chunk * 4 + wave;
        const float2 sj = *(const float2*)(img + (size_t)j * DIM);
        int lo = -1;
        int label = j;
        for (;;) {
            int cand = BATCH;
#pragma unroll
            for (int it = 0; it < 16; ++it) {
                const int i = lane + it * 64;          // always < 1024, in-bounds
                const float2 si = *(const float2*)(img + (size_t)i * DIM);
                if (i < j && i > lo && si.x == sj.x && si.y == sj.y)
                    cand = min(cand, i);
            }
#pragma unroll
            for (int s = 32; s; s >>= 1) cand = min(cand, __shfl_xor(cand, s, 64));
            if (cand >= j) break;                      // no candidate -> label = j
            const float4* rpm = (const float4*)(img + (size_t)cand * DIM);
            const float4* rpj = (const float4*)(img + (size_t)j * DIM);
            bool eq = true;
#pragma unroll
            for (int cc = 0; cc < 3; ++cc) {
                float4 vm = rpm[cc * 64 + lane];
                float4 vj = rpj[cc * 64 + lane];
                eq = eq && (vm.x == vj.x) && (vm.y == vj.y) &&
                     (vm.z == vj.z) && (vm.w == vj.w);
            }
            if (__all(eq)) { label = cand; break; }
            lo = cand;                                 // false positive: rescan above it
        }

        // exact fp32 label logit: scale * dot(img[j], txt[label])
        const float4* aj = (const float4*)(img + (size_t)j * DIM);
        const float4* bl = (const float4*)(txt + (size_t)label * DIM);
        float s = 0.0f;
#pragma unroll
        for (int cc = 0; cc < 3; ++cc) {
            const float4 va = aj[cc * 64 + lane];
            const float4 vb = bl[cc * 64 + lane];
            s += va.x * vb.x + va.y * vb.y + va.z * vb.z + va.w * vb.w;
        }
#pragma unroll
        for (int m = 32; m; m >>= 1) s += __shfl_xor(s, m, 64);
        if (lane == 0) atomicExch(&lval[j], scale * s);
    }

    // last-block tail (R7-verified, no release fence, no spins)
    __syncthreads();
    if (tid == 0)
        isLast = (atomicAdd(tailcnt, 1) == (int)gridDim.x - 1) ? 1 : 0;
    __syncthreads();
    if (!isLast) return;
    __threadfence();   // acquire: invalidate local caches before remote reads

    // thread t combines row t: lse from 4 chunk partials minus label logit
    {
        const float4 m4 = *(const float4*)&pmax[tid * 4];
        const float4 s4 = *(const float4*)&psum[tid * 4];
        const float lv = lval[tid];
        const float gmax = fmaxf(fmaxf(m4.x, m4.y), fmaxf(m4.z, m4.w));
        const float ss = s4.x * __expf(m4.x - gmax) + s4.y * __expf(m4.y - gmax)
                       + s4.z * __expf(m4.z - gmax) + s4.w * __expf(m4.w - gmax);
        float loss = gmax + __logf(ss) - lv;
#pragma unroll
        for (int m = 32; m; m >>= 1) loss += __shfl_xor(loss, m, 64);
        if (lane == 0) part[wave] = loss;
        __syncthreads();
        if (tid == 0) {
            float tot = 0.0f;
#pragma unroll
            for (int w = 0; w < 16; ++w) tot += part[w];
            out[0] = tot * (1.0f / BATCH);
        }
    }
}

extern "C" void kernel_launch(void* const* d_in, const int* in_sizes, int n_in,
                              void* d_out, int out_size, void* d_ws, size_t ws_size,
                              hipStream_t stream) {
    const float* img   = (const float*)d_in[0];
    const float* txt   = (const float*)d_in[1];
    const float* scale = (const float*)d_in[2];
    float* out = (float*)d_out;
    char* ws = (char*)d_ws;

    int*   tailcnt = (int*)(ws + WS_TAIL);
    float* pmax    = (float*)(ws + WS_PMAX);
    float* psum    = (float*)(ws + WS_PSUM);
    float* lval    = (float*)(ws + WS_LVAL);
    unsigned short* txtB = (unsigned short*)(ws + WS_TXTB);

    prep_kernel<<<256, 256, 0, stream>>>(txt, tailcnt, txtB);
    gemm_fused<<<256, 1024, 0, stream>>>(img, txt, scale, txtB,
                                         pmax, psum, lval, tailcnt, out);
}